// Round 17
// baseline (2007.529 us; speedup 1.0000x reference)
//
#include <hip/hip_runtime.h>
#include <hip/hip_bf16.h>

#define VV 50257
#define DD 512
#define TT 1024
#define NBLK 197            // v-blocks of 256 cols (197*256 = 50432 >= VV)
#define PSTR 200            // padded partial stride
#define NBR 64              // recurrence blocks
#define GEMB (NBLK*8)       // 1576 gemm blocks
#define TOTB (NBR + GEMB + TT)   // + 1024 lsm blocks = 2664

typedef __bf16 bf16;
typedef __attribute__((ext_vector_type(8))) __bf16 bf16x8;
typedef __attribute__((ext_vector_type(4))) float f32x4;
typedef __attribute__((ext_vector_type(4))) unsigned int u32x4;

// ---------------- fused kernel: blocks 0..63 = sequential LSTM recurrence (R8 core),
//                  blocks 64..1639 = logits GEMM overlapped under the recurrence,
//                  blocks 1640..2663 = per-row log_softmax gated on GEMM completion ------
// GEMM self-sync: A is read from Hpack -- each u64 = (stamp<<32 | h_bits), so a verified
// stamp guarantees its payload in the SAME load. lsm sync: each gemm block release-adds
// donecnt[my] after its barrier-drained stores; lsm block t acquire-polls ==197.
__global__ __launch_bounds__(512) __attribute__((amdgpu_waves_per_eu(2, 2)))
void mega_kernel(
    const int* __restrict__ idx,
    const float* __restrict__ Wii, const float* __restrict__ Wif,
    const float* __restrict__ Wio, const float* __restrict__ Wig,
    const float* __restrict__ Whi, const float* __restrict__ Whf,
    const float* __restrict__ Who, const float* __restrict__ Whg,
    const float* __restrict__ bi, const float* __restrict__ bfv,
    const float* __restrict__ bo, const float* __restrict__ bg,
    const float* __restrict__ Wout, const float* __restrict__ bout,
    unsigned long long* __restrict__ Hpack,
    float* __restrict__ Cout, float* __restrict__ Pmax, float* __restrict__ Psum,
    int* __restrict__ donecnt, float* __restrict__ out_tail) {
  __shared__ char smem[55296];   // 54 KB -> 2 blocks/CU
  const int tid = threadIdx.x;

  if (blockIdx.x < NBR) {
    // ================= recurrence (R8 structure, single-outstanding poll) =============
    float (*hsh)[DD] = (float(*)[DD])smem;
    int* idxs = (int*)(smem + 4096);
    const int b = blockIdx.x;

    idxs[tid] = idx[tid];
    idxs[tid + 512] = idx[tid + 512];

    const int lane = tid & 63, w = tid >> 6;
    const int hd = (b << 3) + w;

    f32x4 wr0[4], wr1[4];
    #pragma unroll
    for (int gg = 0; gg < 4; ++gg) {
      const float* Wg = (gg == 0) ? Whi : (gg == 1) ? Whf : (gg == 2) ? Who : Whg;
      wr0[gg] = *(const f32x4*)&Wg[(size_t)hd*DD + (lane << 2)];
      wr1[gg] = *(const f32x4*)&Wg[(size_t)hd*DD + 256 + (lane << 2)];
    }
    #pragma unroll
    for (int gg = 0; gg < 4; ++gg) {
      asm volatile("" : "+v"(wr0[gg]));
      asm volatile("" : "+v"(wr1[gg]));
    }

    const float* wxp = nullptr;
    float bias = 0.f;
    if (lane < 4) {
      const float* Wx = (lane == 0) ? Wii : (lane == 1) ? Wif : (lane == 2) ? Wio : Wig;
      const float* bx = (lane == 0) ? bi : (lane == 1) ? bfv : (lane == 2) ? bo : bg;
      wxp = &Wx[(size_t)hd * VV];
      bias = bx[hd];
    }
    float c = 0.f, hout = 0.f;
    __syncthreads();   // idxs ready

    for (int t = 0; t < TT; ++t) {
      float xv = 0.f;
      if (lane < 4) xv = wxp[idxs[t]] + bias;

      float* hb = hsh[t & 1];
      if (t > 0) {
        const unsigned long long* src = &Hpack[(size_t)(t-1)*DD + tid];
        unsigned long long v;
        do {
          asm volatile("global_load_dwordx2 %0, %1, off sc1\n\t"
                       "s_waitcnt vmcnt(0)"
                       : "=v"(v) : "v"(src) : "memory");
        } while (__builtin_expect((unsigned)(v >> 32) != (unsigned)t, 0));
        hb[tid] = __uint_as_float((unsigned)v);
      } else {
        hb[tid] = 0.f;
      }
      __syncthreads();

      const f32x4 h0 = *(const f32x4*)&hb[lane << 2];
      const f32x4 h1 = *(const f32x4*)&hb[256 + (lane << 2)];
      f32x4 m0 = wr0[0]*h0 + wr1[0]*h1;
      f32x4 m1 = wr0[1]*h0 + wr1[1]*h1;
      f32x4 m2 = wr0[2]*h0 + wr1[2]*h1;
      f32x4 m3 = wr0[3]*h0 + wr1[3]*h1;
      float a0 = m0[0]+m0[1]+m0[2]+m0[3];
      float a1 = m1[0]+m1[1]+m1[2]+m1[3];
      float a2 = m2[0]+m2[1]+m2[2]+m2[3];
      float a3 = m3[0]+m3[1]+m3[2]+m3[3];
      #pragma unroll
      for (int mask = 1; mask < 64; mask <<= 1) {
        a0 += __shfl_xor(a0, mask);
        a1 += __shfl_xor(a1, mask);
        a2 += __shfl_xor(a2, mask);
        a3 += __shfl_xor(a3, mask);
      }

      float myacc = (lane == 0) ? a0 : (lane == 1) ? a1 : (lane == 2) ? a2 : a3;
      float pre = myacc + xv;
      bool isg = (lane == 3);
      float e1 = __expf(isg ? -2.f * pre : -pre);
      float rr = 1.f / (1.f + e1);
      float act = isg ? (2.f * rr - 1.f) : rr;

      float ia = __shfl(act, 0);
      float fa = __shfl(act, 1);
      float oa = __shfl(act, 2);
      float ga = __shfl(act, 3);

      if (lane == 0) {
        c = fa * c + ia * ga;
        float e2 = __expf(-2.f * c);
        float th = 2.f / (1.f + e2) - 1.f;
        hout = oa * th;
        unsigned long long pk =
            ((unsigned long long)(unsigned)(t + 1) << 32) |
            (unsigned long long)__float_as_uint(hout);
        __hip_atomic_store(&Hpack[(size_t)t*DD + hd], pk, __ATOMIC_RELAXED,
                           __HIP_MEMORY_SCOPE_AGENT);
        if (t == TT - 1) { out_tail[hd] = hout; out_tail[DD + hd] = c; }
      }
    }
    return;
  }

  if (blockIdx.x >= NBR + GEMB) {
    // ================= gated per-row log_softmax =================
    const int t = blockIdx.x - (NBR + GEMB);
    float* row = Cout + (size_t)t*VV;
    float* sm = (float*)smem;          // [8]
    float* ss = (float*)(smem + 32);   // [8]
    float* lse_p = (float*)(smem + 64);

    if (tid == 0) {
      while (__hip_atomic_load(&donecnt[t >> 7], __ATOMIC_ACQUIRE,
                               __HIP_MEMORY_SCOPE_AGENT) != NBLK)
        __builtin_amdgcn_s_sleep(32);
    }
    __syncthreads();   // donecnt==197: all 197 col-blocks' C/Pmax/Psum visible

    float m = -1e30f, s = 0.f;
    if (tid < NBLK) {
      m = Pmax[(size_t)t*PSTR + tid];
      s = Psum[(size_t)t*PSTR + tid];
    }
    #pragma unroll
    for (int mask = 1; mask < 64; mask <<= 1) {
      float om = __shfl_xor(m, mask);
      float os = __shfl_xor(s, mask);
      float nm = fmaxf(m, om);
      s = s*__expf(m - nm) + os*__expf(om - nm);
      m = nm;
    }
    int wv = tid >> 6;
    if ((tid & 63) == 0) { sm[wv] = m; ss[wv] = s; }
    __syncthreads();
    if (tid == 0) {
      float M = sm[0], S = ss[0];
      for (int i2 = 1; i2 < 8; ++i2) {
        float nm = fmaxf(M, sm[i2]);
        S = S*__expf(M - nm) + ss[i2]*__expf(sm[i2] - nm);
        M = nm;
      }
      *lse_p = M + logf(S);
    }
    __syncthreads();
    const float lse = *lse_p;

    const size_t base = (size_t)t * VV;
    const int head = (int)((4 - (base & 3)) & 3);
    const int nvec = (VV - head) >> 2;
    const int tail0 = head + (nvec << 2);
    if (tid < head) row[tid] -= lse;
    else if (tid >= 508 && (tail0 + (tid - 508)) < VV) row[tail0 + (tid - 508)] -= lse;
    for (int i = tid; i < nvec; i += 512) {
      float* p = &row[head + (i << 2)];
      f32x4 x = *(const f32x4*)p;
      x[0] -= lse; x[1] -= lse; x[2] -= lse; x[3] -= lse;
      *(f32x4*)p = x;
    }
    return;
  }

  // ================= overlapped GEMM: 128 (t) x 256 (v) tile, 8 waves =================
  bf16* As = (bf16*)smem;                          //  8192 B: [128][32]
  bf16* Bs = (bf16*)(smem + 8192);                 // 16384 B: [256][32]
  float (*Cs)[16][72] = (float(*)[16][72])smem;    // 36864 B (reuses As/Bs after k-loop)
  float* partm = (float*)(smem + 36864);           // [2][4][16]
  float* parts = (float*)(smem + 37376);           // [2][4][16]

  const int gb = blockIdx.x - NBR;
  const int my = gb / NBLK;            // 0..7   (row block, dispatched earliest-first)
  const int nb = gb % NBLK;            // 0..196 (col block)
  const int m0 = my << 7, n0 = nb << 8;
  const int w = tid >> 6, l = tid & 63;
  const int wr = w >> 2, wc = w & 3;   // 2x4 wave grid: 64 rows x 64 cols per wave

  // gate: wait until the recurrence reaches step m0+128 (one scalar poll, backoff)
  if (tid == 0) {
    const unsigned long long* gp =
        &Hpack[(size_t)(m0 + 127)*DD + ((unsigned)(nb*67 + my*13) & 511)];
    for (;;) {
      unsigned long long v = __hip_atomic_load(gp, __ATOMIC_RELAXED,
                                               __HIP_MEMORY_SCOPE_AGENT);
      if ((unsigned)(v >> 32) == (unsigned)(m0 + 128)) break;
      __builtin_amdgcn_s_sleep(32);
    }
  }
  __syncthreads();

  // staging roles
  const int ar = tid >> 2;                  // A row 0..127
  const int ac = (tid & 3) << 3;            // A dim chunk (8 u64)
  const unsigned expst = (unsigned)(m0 + ar + 1);
  const unsigned long long* apb = &Hpack[(size_t)(m0 + ar)*DD + ac];
  const int br = tid >> 1;                  // B row 0..255
  const int bc = (tid & 1) << 4;            // B col chunk (16 f32)
  const bool bok = (n0 + br) < VV;
  const float* bpb = &Wout[(size_t)(n0 + br)*DD + bc];

  f32x4 acc[4][4] = {};

  for (int k0 = 0; k0 < DD; k0 += 32) {
    // ---- stage A from Hpack (self-verifying stamps) ----
    u32x4 a0, a1, a2, a3;
    const unsigned long long* ap = apb + k0;
    for (;;) {
      asm volatile("global_load_dwordx4 %0, %4, off sc1\n\t"
                   "global_load_dwordx4 %1, %4, off offset:16 sc1\n\t"
                   "global_load_dwordx4 %2, %4, off offset:32 sc1\n\t"
                   "global_load_dwordx4 %3, %4, off offset:48 sc1\n\t"
                   "s_waitcnt vmcnt(0)"
                   : "=&v"(a0), "=&v"(a1), "=&v"(a2), "=&v"(a3)
                   : "v"(ap) : "memory");
      __builtin_amdgcn_sched_barrier(0);
      if (a0[1] == expst && a0[3] == expst && a1[1] == expst && a1[3] == expst &&
          a2[1] == expst && a2[3] == expst && a3[1] == expst && a3[3] == expst)
        break;
      __builtin_amdgcn_s_sleep(1);
    }
    bf16x8 av;
    av[0] = (bf16)__uint_as_float(a0[0]); av[1] = (bf16)__uint_as_float(a0[2]);
    av[2] = (bf16)__uint_as_float(a1[0]); av[3] = (bf16)__uint_as_float(a1[2]);
    av[4] = (bf16)__uint_as_float(a2[0]); av[5] = (bf16)__uint_as_float(a2[2]);
    av[6] = (bf16)__uint_as_float(a3[0]); av[7] = (bf16)__uint_as_float(a3[2]);
    *(bf16x8*)&As[ar*32 + ac] = av;

    // ---- stage B from Wout (f32 -> bf16 in regs) ----
    bf16x8 bv0, bv1;
    if (bok) {
      const float* bp = bpb + k0;
      f32x4 b0 = *(const f32x4*)bp;
      f32x4 b1 = *(const f32x4*)(bp + 4);
      f32x4 b2 = *(const f32x4*)(bp + 8);
      f32x4 b3 = *(const f32x4*)(bp + 12);
      bv0[0]=(bf16)b0[0]; bv0[1]=(bf16)b0[1]; bv0[2]=(bf16)b0[2]; bv0[3]=(bf16)b0[3];
      bv0[4]=(bf16)b1[0]; bv0[5]=(bf16)b1[1]; bv0[6]=(bf16)b1[2]; bv0[7]=(bf16)b1[3];
      bv1[0]=(bf16)b2[0]; bv1[1]=(bf16)b2[1]; bv1[2]=(bf16)b2[2]; bv1[3]=(bf16)b2[3];
      bv1[4]=(bf16)b3[0]; bv1[5]=(bf16)b3[1]; bv1[6]=(bf16)b3[2]; bv1[7]=(bf16)b3[3];
    } else {
      #pragma unroll
      for (int e = 0; e < 8; ++e) { bv0[e] = (bf16)0.f; bv1[e] = (bf16)0.f; }
    }
    *(bf16x8*)&Bs[br*32 + bc] = bv0;
    *(bf16x8*)&Bs[br*32 + bc + 8] = bv1;

    __syncthreads();
    bf16x8 af[4], bfr[4];
    #pragma unroll
    for (int mi = 0; mi < 4; ++mi)
      af[mi] = *(const bf16x8*)&As[(wr*64 + mi*16 + (l & 15))*32 + (l >> 4)*8];
    #pragma unroll
    for (int ni = 0; ni < 4; ++ni)
      bfr[ni] = *(const bf16x8*)&Bs[(wc*64 + ni*16 + (l & 15))*32 + (l >> 4)*8];
    #pragma unroll
    for (int mi = 0; mi < 4; ++mi)
      #pragma unroll
      for (int ni = 0; ni < 4; ++ni)
        acc[mi][ni] = __builtin_amdgcn_mfma_f32_16x16x32_bf16(af[mi], bfr[ni], acc[mi][ni], 0, 0, 0);
    __syncthreads();
  }

  // ---- epilogue: bias, softmax partials, staged contiguous writes ----
  float bbv[4];
  bool colok[4];
  #pragma unroll
  for (int ni = 0; ni < 4; ++ni) {
    int col = n0 + wc*64 + ni*16 + (l & 15);
    colok[ni] = (col < VV);
    bbv[ni] = colok[ni] ? bout[col] : 0.f;
  }

  #pragma unroll
  for (int mi = 0; mi < 4; ++mi) {
    #pragma unroll
    for (int ni = 0; ni < 4; ++ni)
      #pragma unroll
      for (int r = 0; r < 4; ++r)
        Cs[w][(l >> 4)*4 + r][ni*16 + (l & 15)] = acc[mi][ni][r] + bbv[ni];

    #pragma unroll
    for (int r = 0; r < 4; ++r) {
      float v0 = colok[0] ? acc[mi][0][r] + bbv[0] : -1e30f;
      float v1 = colok[1] ? acc[mi][1][r] + bbv[1] : -1e30f;
      float v2 = colok[2] ? acc[mi][2][r] + bbv[2] : -1e30f;
      float v3 = colok[3] ? acc[mi][3][r] + bbv[3] : -1e30f;
      float pm = fmaxf(fmaxf(v0, v1), fmaxf(v2, v3));
      #pragma unroll
      for (int mk = 1; mk < 16; mk <<= 1) pm = fmaxf(pm, __shfl_xor(pm, mk));
      float ps = __expf(v0 - pm) + __expf(v1 - pm) + __expf(v2 - pm) + __expf(v3 - pm);
      #pragma unroll
      for (int mk = 1; mk < 16; mk <<= 1) ps += __shfl_xor(ps, mk);
      if ((l & 15) == 0) {
        partm[(wr*4 + wc)*16 + (l >> 4)*4 + r] = pm;
        parts[(wr*4 + wc)*16 + (l >> 4)*4 + r] = ps;
      }
    }
    __syncthreads();
    if (tid < 32) {
      int wr2 = tid >> 4, row16 = tid & 15;
      float M = -1e30f, S = 0.f;
      #pragma unroll
      for (int q = 0; q < 4; ++q) {
        float mm = partm[(wr2*4 + q)*16 + row16];
        float sp = parts[(wr2*4 + q)*16 + row16];
        float nm = fmaxf(M, mm);
        S = S*__expf(M - nm) + sp*__expf(mm - nm);
        M = nm;
      }
      int gr = m0 + wr2*64 + mi*16 + row16;
      Pmax[(size_t)gr*PSTR + nb] = M;
      Psum[(size_t)gr*PSTR + nb] = S;
    }

    const int rbase = m0 + wr*64 + mi*16;
    #pragma unroll
    for (int i = 0; i < 4; ++i) {
      int idx2 = i*64 + l;
      int row = idx2 >> 4, quad = idx2 & 15;
      int col = n0 + wc*64 + quad*4;
      f32x4 v = *(const f32x4*)&Cs[w][row][quad*4];
      float* dst = &Cout[(size_t)(rbase + row)*VV + col];
      if (col + 3 < VV) {
        asm volatile("global_store_dwordx4 %0, %1, off"
                     :: "v"(dst), "v"(v) : "memory");
      } else {
        #pragma unroll
        for (int e = 0; e < 4; ++e)
          if (col + e < VV) dst[e] = v[e];
      }
    }
    __syncthreads();
  }

  // signal completion: barrier above drained all waves' stores; release-add publishes
  if (tid == 0)
    __hip_atomic_fetch_add(&donecnt[my], 1, __ATOMIC_RELEASE, __HIP_MEMORY_SCOPE_AGENT);
}

extern "C" void kernel_launch(void* const* d_in, const int* in_sizes, int n_in,
                              void* d_out, int out_size, void* d_ws, size_t ws_size,
                              hipStream_t stream) {
  const int*   idx  = (const int*)d_in[0];
  const float* Wii  = (const float*)d_in[1];
  const float* Wif  = (const float*)d_in[2];
  const float* Wio  = (const float*)d_in[3];
  const float* Wig  = (const float*)d_in[4];
  const float* Whi  = (const float*)d_in[5];
  const float* Whf  = (const float*)d_in[6];
  const float* Who  = (const float*)d_in[7];
  const float* Whg  = (const float*)d_in[8];
  const float* bi   = (const float*)d_in[9];
  const float* bfv  = (const float*)d_in[10];
  const float* bo   = (const float*)d_in[11];
  const float* bg   = (const float*)d_in[12];
  const float* Wout = (const float*)d_in[13];
  const float* bout = (const float*)d_in[14];
  float* out = (float*)d_out;

  // ws layout:
  //   [0, 4194304)           : Hpack (TT*DD u64: stamp<<32 | h bits)
  //   [4194304, 5013504)     : Pmax (1024*200 f32)
  //   [5013504, 5832704)     : Psum (1024*200 f32)
  //   [5832704, 5832736)     : donecnt (8 x int)
  char* ws = (char*)d_ws;
  unsigned long long* Hpack = (unsigned long long*)ws;
  float* Pmax = (float*)(ws + 4194304);
  float* Psum = (float*)(ws + 5013504);
  int*   donecnt = (int*)(ws + 5832704);

  hipMemsetAsync(Hpack, 0, (size_t)TT*DD*8, stream);   // fresh stamps every launch
  hipMemsetAsync(donecnt, 0, 32, stream);              // fresh completion counters
  mega_kernel<<<TOTB, 512, 0, stream>>>(
      idx, Wii, Wif, Wio, Wig, Whi, Whf, Who, Whg, bi, bfv, bo, bg, Wout, bout,
      Hpack, out, Pmax, Psum, donecnt, out + (size_t)TT*VV);
}

// Round 18
// 1945.973 us; speedup vs baseline: 1.0316x; 1.0316x over previous
//
#include <hip/hip_runtime.h>
#include <hip/hip_bf16.h>

#define VV 50257
#define DD 512
#define TT 1024
#define NBLK 197            // v-blocks of 256 cols (197*256 = 50432 >= VV)
#define PSTR 200            // padded partial stride
#define NBR 64              // recurrence blocks
#define GEMB (NBLK*8)       // 1576 gemm blocks
#define TOTB (NBR + GEMB)   // 1640

typedef __bf16 bf16;
typedef __attribute__((ext_vector_type(8))) __bf16 bf16x8;
typedef __attribute__((ext_vector_type(4))) float f32x4;
typedef __attribute__((ext_vector_type(4))) unsigned int u32x4;

// ---------------- fused kernel: blocks 0..63 = sequential LSTM recurrence (R8 core),
//                  blocks 64..1639 = logits GEMM overlapped under the recurrence ---------
// GEMM self-sync: A is read from Hpack -- each u64 = (stamp<<32 | h_bits), so a verified
// stamp guarantees its payload in the SAME load (no cross-address ordering assumptions).
// Per-block gate: thread0 polls ONE stamp of its last row with s_sleep backoff (no storm).
__global__ __launch_bounds__(512) __attribute__((amdgpu_waves_per_eu(2, 2)))
void mega_kernel(
    const int* __restrict__ idx,
    const float* __restrict__ Wii, const float* __restrict__ Wif,
    const float* __restrict__ Wio, const float* __restrict__ Wig,
    const float* __restrict__ Whi, const float* __restrict__ Whf,
    const float* __restrict__ Who, const float* __restrict__ Whg,
    const float* __restrict__ bi, const float* __restrict__ bfv,
    const float* __restrict__ bo, const float* __restrict__ bg,
    const float* __restrict__ Wout, const float* __restrict__ bout,
    unsigned long long* __restrict__ Hpack,
    float* __restrict__ Cout, float* __restrict__ Pmax, float* __restrict__ Psum,
    float* __restrict__ out_tail) {
  __shared__ char smem[55296];   // 54 KB -> 2 blocks/CU
  const int tid = threadIdx.x;

  if (blockIdx.x < NBR) {
    // ================= recurrence (R8 structure, single-outstanding poll) =============
    float (*hsh)[DD] = (float(*)[DD])smem;
    int* idxs = (int*)(smem + 4096);
    const int b = blockIdx.x;

    idxs[tid] = idx[tid];
    idxs[tid + 512] = idx[tid + 512];

    const int lane = tid & 63, w = tid >> 6;
    const int hd = (b << 3) + w;

    f32x4 wr0[4], wr1[4];
    #pragma unroll
    for (int gg = 0; gg < 4; ++gg) {
      const float* Wg = (gg == 0) ? Whi : (gg == 1) ? Whf : (gg == 2) ? Who : Whg;
      wr0[gg] = *(const f32x4*)&Wg[(size_t)hd*DD + (lane << 2)];
      wr1[gg] = *(const f32x4*)&Wg[(size_t)hd*DD + 256 + (lane << 2)];
    }
    #pragma unroll
    for (int gg = 0; gg < 4; ++gg) {
      asm volatile("" : "+v"(wr0[gg]));
      asm volatile("" : "+v"(wr1[gg]));
    }

    const float* wxp = nullptr;
    float bias = 0.f;
    if (lane < 4) {
      const float* Wx = (lane == 0) ? Wii : (lane == 1) ? Wif : (lane == 2) ? Wio : Wig;
      const float* bx = (lane == 0) ? bi : (lane == 1) ? bfv : (lane == 2) ? bo : bg;
      wxp = &Wx[(size_t)hd * VV];
      bias = bx[hd];
    }
    float c = 0.f, hout = 0.f;
    __syncthreads();   // idxs ready

    for (int t = 0; t < TT; ++t) {
      float xv = 0.f;
      if (lane < 4) xv = wxp[idxs[t]] + bias;

      float* hb = hsh[t & 1];
      if (t > 0) {
        const unsigned long long* src = &Hpack[(size_t)(t-1)*DD + tid];
        unsigned long long v;
        do {
          asm volatile("global_load_dwordx2 %0, %1, off sc1\n\t"
                       "s_waitcnt vmcnt(0)"
                       : "=v"(v) : "v"(src) : "memory");
        } while (__builtin_expect((unsigned)(v >> 32) != (unsigned)t, 0));
        hb[tid] = __uint_as_float((unsigned)v);
      } else {
        hb[tid] = 0.f;
      }
      __syncthreads();

      const f32x4 h0 = *(const f32x4*)&hb[lane << 2];
      const f32x4 h1 = *(const f32x4*)&hb[256 + (lane << 2)];
      f32x4 m0 = wr0[0]*h0 + wr1[0]*h1;
      f32x4 m1 = wr0[1]*h0 + wr1[1]*h1;
      f32x4 m2 = wr0[2]*h0 + wr1[2]*h1;
      f32x4 m3 = wr0[3]*h0 + wr1[3]*h1;
      float a0 = m0[0]+m0[1]+m0[2]+m0[3];
      float a1 = m1[0]+m1[1]+m1[2]+m1[3];
      float a2 = m2[0]+m2[1]+m2[2]+m2[3];
      float a3 = m3[0]+m3[1]+m3[2]+m3[3];
      #pragma unroll
      for (int mask = 1; mask < 64; mask <<= 1) {
        a0 += __shfl_xor(a0, mask);
        a1 += __shfl_xor(a1, mask);
        a2 += __shfl_xor(a2, mask);
        a3 += __shfl_xor(a3, mask);
      }

      float myacc = (lane == 0) ? a0 : (lane == 1) ? a1 : (lane == 2) ? a2 : a3;
      float pre = myacc + xv;
      bool isg = (lane == 3);
      float e1 = __expf(isg ? -2.f * pre : -pre);
      float rr = 1.f / (1.f + e1);
      float act = isg ? (2.f * rr - 1.f) : rr;

      float ia = __shfl(act, 0);
      float fa = __shfl(act, 1);
      float oa = __shfl(act, 2);
      float ga = __shfl(act, 3);

      if (lane == 0) {
        c = fa * c + ia * ga;
        float e2 = __expf(-2.f * c);
        float th = 2.f / (1.f + e2) - 1.f;
        hout = oa * th;
        unsigned long long pk =
            ((unsigned long long)(unsigned)(t + 1) << 32) |
            (unsigned long long)__float_as_uint(hout);
        __hip_atomic_store(&Hpack[(size_t)t*DD + hd], pk, __ATOMIC_RELAXED,
                           __HIP_MEMORY_SCOPE_AGENT);
        if (t == TT - 1) { out_tail[hd] = hout; out_tail[DD + hd] = c; }
      }
    }
    return;
  }

  // ================= overlapped GEMM: 128 (t) x 256 (v) tile, 8 waves =================
  bf16* As = (bf16*)smem;                          //  8192 B: [128][32]
  bf16* Bs = (bf16*)(smem + 8192);                 // 16384 B: [256][32]
  float (*Cs)[16][72] = (float(*)[16][72])smem;    // 36864 B (reuses As/Bs after k-loop)
  float* partm = (float*)(smem + 36864);           // [2][4][16]
  float* parts = (float*)(smem + 37376);           // [2][4][16]

  const int gb = blockIdx.x - NBR;
  const int my = gb / NBLK;            // 0..7   (row block, dispatched earliest-first)
  const int nb = gb % NBLK;            // 0..196 (col block)
  const int m0 = my << 7, n0 = nb << 8;
  const int w = tid >> 6, l = tid & 63;
  const int wr = w >> 2, wc = w & 3;   // 2x4 wave grid: 64 rows x 64 cols per wave

  // gate: wait until the recurrence reaches step m0+128 (one scalar poll, backoff)
  if (tid == 0) {
    const unsigned long long* gp =
        &Hpack[(size_t)(m0 + 127)*DD + ((unsigned)(nb*67 + my*13) & 511)];
    for (;;) {
      unsigned long long v = __hip_atomic_load(gp, __ATOMIC_RELAXED,
                                               __HIP_MEMORY_SCOPE_AGENT);
      if ((unsigned)(v >> 32) == (unsigned)(m0 + 128)) break;
      __builtin_amdgcn_s_sleep(32);
    }
  }
  __syncthreads();

  // staging roles
  const int ar = tid >> 2;                  // A row 0..127
  const int ac = (tid & 3) << 3;            // A dim chunk (8 u64)
  const unsigned expst = (unsigned)(m0 + ar + 1);
  const unsigned long long* apb = &Hpack[(size_t)(m0 + ar)*DD + ac];
  const int br = tid >> 1;                  // B row 0..255
  const int bc = (tid & 1) << 4;            // B col chunk (16 f32)
  const bool bok = (n0 + br) < VV;
  const float* bpb = &Wout[(size_t)(n0 + br)*DD + bc];

  f32x4 acc[4][4] = {};

  for (int k0 = 0; k0 < DD; k0 += 32) {
    // ---- stage A from Hpack (self-verifying stamps) ----
    u32x4 a0, a1, a2, a3;
    const unsigned long long* ap = apb + k0;
    for (;;) {
      asm volatile("global_load_dwordx4 %0, %4, off sc1\n\t"
                   "global_load_dwordx4 %1, %4, off offset:16 sc1\n\t"
                   "global_load_dwordx4 %2, %4, off offset:32 sc1\n\t"
                   "global_load_dwordx4 %3, %4, off offset:48 sc1\n\t"
                   "s_waitcnt vmcnt(0)"
                   : "=&v"(a0), "=&v"(a1), "=&v"(a2), "=&v"(a3)
                   : "v"(ap) : "memory");
      __builtin_amdgcn_sched_barrier(0);
      if (a0[1] == expst && a0[3] == expst && a1[1] == expst && a1[3] == expst &&
          a2[1] == expst && a2[3] == expst && a3[1] == expst && a3[3] == expst)
        break;
      __builtin_amdgcn_s_sleep(1);
    }
    bf16x8 av;
    av[0] = (bf16)__uint_as_float(a0[0]); av[1] = (bf16)__uint_as_float(a0[2]);
    av[2] = (bf16)__uint_as_float(a1[0]); av[3] = (bf16)__uint_as_float(a1[2]);
    av[4] = (bf16)__uint_as_float(a2[0]); av[5] = (bf16)__uint_as_float(a2[2]);
    av[6] = (bf16)__uint_as_float(a3[0]); av[7] = (bf16)__uint_as_float(a3[2]);
    *(bf16x8*)&As[ar*32 + ac] = av;

    // ---- stage B from Wout (f32 -> bf16 in regs) ----
    bf16x8 bv0, bv1;
    if (bok) {
      const float* bp = bpb + k0;
      f32x4 b0 = *(const f32x4*)bp;
      f32x4 b1 = *(const f32x4*)(bp + 4);
      f32x4 b2 = *(const f32x4*)(bp + 8);
      f32x4 b3 = *(const f32x4*)(bp + 12);
      bv0[0]=(bf16)b0[0]; bv0[1]=(bf16)b0[1]; bv0[2]=(bf16)b0[2]; bv0[3]=(bf16)b0[3];
      bv0[4]=(bf16)b1[0]; bv0[5]=(bf16)b1[1]; bv0[6]=(bf16)b1[2]; bv0[7]=(bf16)b1[3];
      bv1[0]=(bf16)b2[0]; bv1[1]=(bf16)b2[1]; bv1[2]=(bf16)b2[2]; bv1[3]=(bf16)b2[3];
      bv1[4]=(bf16)b3[0]; bv1[5]=(bf16)b3[1]; bv1[6]=(bf16)b3[2]; bv1[7]=(bf16)b3[3];
    } else {
      #pragma unroll
      for (int e = 0; e < 8; ++e) { bv0[e] = (bf16)0.f; bv1[e] = (bf16)0.f; }
    }
    *(bf16x8*)&Bs[br*32 + bc] = bv0;
    *(bf16x8*)&Bs[br*32 + bc + 8] = bv1;

    __syncthreads();
    bf16x8 af[4], bfr[4];
    #pragma unroll
    for (int mi = 0; mi < 4; ++mi)
      af[mi] = *(const bf16x8*)&As[(wr*64 + mi*16 + (l & 15))*32 + (l >> 4)*8];
    #pragma unroll
    for (int ni = 0; ni < 4; ++ni)
      bfr[ni] = *(const bf16x8*)&Bs[(wc*64 + ni*16 + (l & 15))*32 + (l >> 4)*8];
    #pragma unroll
    for (int mi = 0; mi < 4; ++mi)
      #pragma unroll
      for (int ni = 0; ni < 4; ++ni)
        acc[mi][ni] = __builtin_amdgcn_mfma_f32_16x16x32_bf16(af[mi], bfr[ni], acc[mi][ni], 0, 0, 0);
    __syncthreads();
  }

  // ---- epilogue: bias, softmax partials, staged contiguous writes ----
  float bbv[4];
  bool colok[4];
  #pragma unroll
  for (int ni = 0; ni < 4; ++ni) {
    int col = n0 + wc*64 + ni*16 + (l & 15);
    colok[ni] = (col < VV);
    bbv[ni] = colok[ni] ? bout[col] : 0.f;
  }

  #pragma unroll
  for (int mi = 0; mi < 4; ++mi) {
    #pragma unroll
    for (int ni = 0; ni < 4; ++ni)
      #pragma unroll
      for (int r = 0; r < 4; ++r)
        Cs[w][(l >> 4)*4 + r][ni*16 + (l & 15)] = acc[mi][ni][r] + bbv[ni];

    #pragma unroll
    for (int r = 0; r < 4; ++r) {
      float v0 = colok[0] ? acc[mi][0][r] + bbv[0] : -1e30f;
      float v1 = colok[1] ? acc[mi][1][r] + bbv[1] : -1e30f;
      float v2 = colok[2] ? acc[mi][2][r] + bbv[2] : -1e30f;
      float v3 = colok[3] ? acc[mi][3][r] + bbv[3] : -1e30f;
      float pm = fmaxf(fmaxf(v0, v1), fmaxf(v2, v3));
      #pragma unroll
      for (int mk = 1; mk < 16; mk <<= 1) pm = fmaxf(pm, __shfl_xor(pm, mk));
      float ps = __expf(v0 - pm) + __expf(v1 - pm) + __expf(v2 - pm) + __expf(v3 - pm);
      #pragma unroll
      for (int mk = 1; mk < 16; mk <<= 1) ps += __shfl_xor(ps, mk);
      if ((l & 15) == 0) {
        partm[(wr*4 + wc)*16 + (l >> 4)*4 + r] = pm;
        parts[(wr*4 + wc)*16 + (l >> 4)*4 + r] = ps;
      }
    }
    __syncthreads();
    if (tid < 32) {
      int wr2 = tid >> 4, row16 = tid & 15;
      float M = -1e30f, S = 0.f;
      #pragma unroll
      for (int q = 0; q < 4; ++q) {
        float mm = partm[(wr2*4 + q)*16 + row16];
        float sp = parts[(wr2*4 + q)*16 + row16];
        float nm = fmaxf(M, mm);
        S = S*__expf(M - nm) + sp*__expf(mm - nm);
        M = nm;
      }
      int gr = m0 + wr2*64 + mi*16 + row16;
      Pmax[(size_t)gr*PSTR + nb] = M;
      Psum[(size_t)gr*PSTR + nb] = S;
    }

    const int rbase = m0 + wr*64 + mi*16;
    #pragma unroll
    for (int i = 0; i < 4; ++i) {
      int idx2 = i*64 + l;
      int row = idx2 >> 4, quad = idx2 & 15;
      int col = n0 + wc*64 + quad*4;
      f32x4 v = *(const f32x4*)&Cs[w][row][quad*4];
      float* dst = &Cout[(size_t)(rbase + row)*VV + col];
      if (col + 3 < VV) {
        asm volatile("global_store_dwordx4 %0, %1, off"
                     :: "v"(dst), "v"(v) : "memory");
      } else {
        #pragma unroll
        for (int e = 0; e < 4; ++e)
          if (col + e < VV) dst[e] = v[e];
      }
    }
    __syncthreads();
  }
}

// ---------------- phase 2: single-pass log_softmax from gemm partials ------------------
__global__ __launch_bounds__(512) void lsm_kernel(float* __restrict__ logits,
                                                  const float* __restrict__ Pmax,
                                                  const float* __restrict__ Psum) {
  const int t = blockIdx.x, tid = threadIdx.x;
  float* row = logits + (size_t)t*VV;

  float m = -1e30f, s = 0.f;
  if (tid < NBLK) {
    m = Pmax[(size_t)t*PSTR + tid];
    s = Psum[(size_t)t*PSTR + tid];
  }
  #pragma unroll
  for (int mask = 1; mask < 64; mask <<= 1) {
    float om = __shfl_xor(m, mask);
    float os = __shfl_xor(s, mask);
    float nm = fmaxf(m, om);
    s = s*__expf(m - nm) + os*__expf(om - nm);
    m = nm;
  }
  __shared__ float sm[8], ss[8], lse_sh;
  int wv = tid >> 6;
  if ((tid & 63) == 0) { sm[wv] = m; ss[wv] = s; }
  __syncthreads();
  if (tid == 0) {
    float M = sm[0], S = ss[0];
    for (int i2 = 1; i2 < 8; ++i2) {
      float nm = fmaxf(M, sm[i2]);
      S = S*__expf(M - nm) + ss[i2]*__expf(sm[i2] - nm);
      M = nm;
    }
    lse_sh = M + logf(S);
  }
  __syncthreads();
  const float lse = lse_sh;

  const size_t base = (size_t)t * VV;
  const int head = (int)((4 - (base & 3)) & 3);
  const int nvec = (VV - head) >> 2;
  const int tail0 = head + (nvec << 2);
  if (tid < head) row[tid] -= lse;
  else if (tid >= 508 && (tail0 + (tid - 508)) < VV) row[tail0 + (tid - 508)] -= lse;
  for (int i = tid; i < nvec; i += 512) {
    float* p = &row[head + (i << 2)];
    f32x4 x = *(const f32x4*)p;
    x[0] -= lse; x[1] -= lse; x[2] -= lse; x[3] -= lse;
    *(f32x4*)p = x;
  }
}

extern "C" void kernel_launch(void* const* d_in, const int* in_sizes, int n_in,
                              void* d_out, int out_size, void* d_ws, size_t ws_size,
                              hipStream_t stream) {
  const int*   idx  = (const int*)d_in[0];
  const float* Wii  = (const float*)d_in[1];
  const float* Wif  = (const float*)d_in[2];
  const float* Wio  = (const float*)d_in[3];
  const float* Wig  = (const float*)d_in[4];
  const float* Whi  = (const float*)d_in[5];
  const float* Whf  = (const float*)d_in[6];
  const float* Who  = (const float*)d_in[7];
  const float* Whg  = (const float*)d_in[8];
  const float* bi   = (const float*)d_in[9];
  const float* bfv  = (const float*)d_in[10];
  const float* bo   = (const float*)d_in[11];
  const float* bg   = (const float*)d_in[12];
  const float* Wout = (const float*)d_in[13];
  const float* bout = (const float*)d_in[14];
  float* out = (float*)d_out;

  // ws layout:
  //   [0, 4194304)           : Hpack (TT*DD u64: stamp<<32 | h bits)
  //   [4194304, 5013504)     : Pmax (1024*200 f32)
  //   [5013504, 5832704)     : Psum (1024*200 f32)
  char* ws = (char*)d_ws;
  unsigned long long* Hpack = (unsigned long long*)ws;
  float* Pmax = (float*)(ws + 4194304);
  float* Psum = (float*)(ws + 5013504);

  hipMemsetAsync(Hpack, 0, (size_t)TT*DD*8, stream);   // fresh stamps every launch
  mega_kernel<<<TOTB, 512, 0, stream>>>(
      idx, Wii, Wif, Wio, Wig, Whi, Whf, Who, Whg, bi, bfv, bo, bg, Wout, bout,
      Hpack, out, Pmax, Psum, out + (size_t)TT*VV);
  lsm_kernel<<<TT, 512, 0, stream>>>(out, Pmax, Psum);
}